// Round 8
// baseline (161.594 us; speedup 1.0000x reference)
//
#include <hip/hip_runtime.h>

#define BS 64
#define NN 2048
#define DD 512
#define ROWS 32
#define BPB (NN / ROWS)   // blocks per batch in pass 2 = 64

typedef float f32x4 __attribute__((ext_vector_type(4)));

// ---------- Kernel 1: content scores ----------
__global__ __launch_bounds__(256) void k_score(const float* __restrict__ M,
                                               const float* __restrict__ k,
                                               const float* __restrict__ beta,
                                               float* __restrict__ score) {
    int wave = threadIdx.x >> 6;
    int lane = threadIdx.x & 63;
    int row  = blockIdx.x * 4 + wave;           // [0, BS*NN)
    int b    = row >> 11;                        // row / NN
    const float4* Mr = (const float4*)(M + (size_t)row * DD);
    const float4* kr = (const float4*)(k + (size_t)b * DD);
    float dot = 0.f, ssm = 0.f, ssk = 0.f;
#pragma unroll
    for (int i = 0; i < 2; ++i) {
        int idx = lane + i * 64;                 // 0..127 float4s
        float4 m4 = Mr[idx];
        float4 k4 = kr[idx];
        dot += m4.x * k4.x + m4.y * k4.y + m4.z * k4.z + m4.w * k4.w;
        ssm += m4.x * m4.x + m4.y * m4.y + m4.z * m4.z + m4.w * m4.w;
        ssk += k4.x * k4.x + k4.y * k4.y + k4.z * k4.z + k4.w * k4.w;
    }
#pragma unroll
    for (int off = 32; off > 0; off >>= 1) {
        dot += __shfl_xor(dot, off);
        ssm += __shfl_xor(ssm, off);
        ssk += __shfl_xor(ssk, off);
    }
    if (lane == 0) {
        score[row] = beta[b] * dot * rsqrtf(ssm * ssk);
    }
}

// ---------- Kernel 2: softmax + gate + circular conv + sharpen ----------
__device__ __forceinline__ float block_max(float v) {
    __shared__ float sm[4];
    int lane = threadIdx.x & 63, wid = threadIdx.x >> 6;
#pragma unroll
    for (int off = 32; off > 0; off >>= 1) v = fmaxf(v, __shfl_xor(v, off));
    if (lane == 0) sm[wid] = v;
    __syncthreads();
    v = fmaxf(fmaxf(sm[0], sm[1]), fmaxf(sm[2], sm[3]));
    __syncthreads();
    return v;
}
__device__ __forceinline__ float block_sum(float v) {
    __shared__ float sm[4];
    int lane = threadIdx.x & 63, wid = threadIdx.x >> 6;
#pragma unroll
    for (int off = 32; off > 0; off >>= 1) v += __shfl_xor(v, off);
    if (lane == 0) sm[wid] = v;
    __syncthreads();
    v = sm[0] + sm[1] + sm[2] + sm[3];
    __syncthreads();
    return v;
}

__global__ __launch_bounds__(256) void k_weights(const float* __restrict__ score,
                                                 const float* __restrict__ gp,
                                                 const float* __restrict__ sp,
                                                 const float* __restrict__ yp,
                                                 const float* __restrict__ w_prev,
                                                 float* __restrict__ w_out) {
    __shared__ float v[NN];
    int b = blockIdx.x, t = threadIdx.x;
    float g  = gp[b], y = yp[b];
    float s0 = sp[b * 3 + 0], s1 = sp[b * 3 + 1], s2 = sp[b * 3 + 2];

    float loc[8];
    float mx = -1e30f;
#pragma unroll
    for (int i = 0; i < 8; ++i) {
        loc[i] = score[b * NN + t * 8 + i];
        mx = fmaxf(mx, loc[i]);
    }
    mx = block_max(mx);
    float sum = 0.f;
#pragma unroll
    for (int i = 0; i < 8; ++i) {
        loc[i] = __expf(loc[i] - mx);
        sum += loc[i];
    }
    sum = block_sum(sum);
    float inv = 1.f / sum;
#pragma unroll
    for (int i = 0; i < 8; ++i) {
        int n = t * 8 + i;
        v[n] = g * loc[i] * inv + (1.f - g) * w_prev[b * NN + n];
    }
    __syncthreads();
    float u[8];
    float psum = 0.f;
#pragma unroll
    for (int i = 0; i < 8; ++i) {
        int n  = t * 8 + i;
        int nm = (n == 0) ? NN - 1 : n - 1;
        int np = (n == NN - 1) ? 0 : n + 1;
        float uu = s2 * v[nm] + s1 * v[n] + s0 * v[np];
        uu = powf(uu, y);
        u[i] = uu;
        psum += uu;
    }
    psum = block_sum(psum);
    float pin = 1.f / psum;
#pragma unroll
    for (int i = 0; i < 8; ++i) w_out[b * NN + t * 8 + i] = u[i] * pin;
}

// ---------- Kernel 3: write M_next + per-block partial r ----------
// Reversed block order; PLAIN loads and PLAIN stores (L2 write-combining);
// 8-deep load staging; 32 rows/block (grid 4096) for latency hiding.
__global__ __launch_bounds__(256) void k_readwrite(const float* __restrict__ M,
                                                   const float* __restrict__ e,
                                                   const float* __restrict__ a,
                                                   const float* __restrict__ w,
                                                   float* __restrict__ part,
                                                   float* __restrict__ Mn) {
    int blk = (int)gridDim.x - 1 - (int)blockIdx.x;   // reverse for L3 LRU
    int b   = blk / BPB;
    int n0  = (blk % BPB) * ROWS;
    int t   = threadIdx.x;
    int c   = t & 127;   // float4 column
    int rh  = t >> 7;    // 0 or 1 (row parity)

    const f32x4* e4 = (const f32x4*)(e + (size_t)b * DD);
    const f32x4* a4 = (const f32x4*)(a + (size_t)b * DD);
    f32x4 ev = e4[c], av = a4[c];
    f32x4 acc = (f32x4)(0.f);

    const f32x4* Mb  = (const f32x4*)(M  + ((size_t)b * NN + n0) * DD);
    f32x4*       Mnb = (f32x4*)      (Mn + ((size_t)b * NN + n0) * DD);
    const float* wb  = w + (size_t)b * NN + n0;

#pragma unroll
    for (int i = 0; i < ROWS / 16; ++i) {
        float wv[8];
        f32x4 m4[8];
#pragma unroll
        for (int j = 0; j < 8; ++j) {
            int rr = (i * 8 + j) * 2 + rh;
            wv[j] = wb[rr];
            m4[j] = Mb[(size_t)rr * 128 + c];
        }
#pragma unroll
        for (int j = 0; j < 8; ++j) {
            int rr = (i * 8 + j) * 2 + rh;
            acc += wv[j] * m4[j];
            f32x4 o = m4[j] * (1.f - wv[j] * ev) + wv[j] * av;
            Mnb[(size_t)rr * 128 + c] = o;
        }
    }

    __shared__ f32x4 sacc[128];
    if (rh == 1) sacc[c] = acc;
    __syncthreads();
    if (rh == 0) {
        acc += sacc[c];
        ((f32x4*)(part + (size_t)blk * DD))[c] = acc;
    }
}

// ---------- Kernel 4: reduce partial r ----------
__global__ __launch_bounds__(256) void k_reduce(const float* __restrict__ part,
                                               float* __restrict__ r) {
    int b  = blockIdx.x;
    int t  = threadIdx.x;
    int c  = t & 127;
    int rh = t >> 7;
    const f32x4* pb = (const f32x4*)(part + (size_t)b * BPB * DD);
    f32x4 acc = (f32x4)(0.f);
    for (int j = rh * (BPB / 2); j < (rh + 1) * (BPB / 2); ++j) {
        acc += pb[(size_t)j * 128 + c];
    }
    __shared__ f32x4 sacc[128];
    if (rh == 1) sacc[c] = acc;
    __syncthreads();
    if (rh == 0) {
        acc += sacc[c];
        ((f32x4*)(r + (size_t)b * DD))[c] = acc;
    }
}

extern "C" void kernel_launch(void* const* d_in, const int* in_sizes, int n_in,
                              void* d_out, int out_size, void* d_ws, size_t ws_size,
                              hipStream_t stream) {
    const float* M      = (const float*)d_in[0];
    const float* k      = (const float*)d_in[1];
    const float* beta   = (const float*)d_in[2];
    const float* g      = (const float*)d_in[3];
    const float* s      = (const float*)d_in[4];
    const float* y      = (const float*)d_in[5];
    const float* e      = (const float*)d_in[6];
    const float* a      = (const float*)d_in[7];
    const float* w_prev = (const float*)d_in[8];

    float* out = (float*)d_out;
    float* r   = out;                       // [BS, DD]
    float* w   = out + BS * DD;             // [BS, NN]
    float* Mn  = out + BS * DD + BS * NN;   // [BS, NN, DD]

    float* score = (float*)d_ws;                 // BS*NN floats   (512 KB)
    float* part  = score + BS * NN;              // BS*BPB*DD floats (8 MB)

    k_score    <<<BS * NN / 4, 256, 0, stream>>>(M, k, beta, score);
    k_weights  <<<BS,          256, 0, stream>>>(score, g, s, y, w_prev, w);
    k_readwrite<<<BS * BPB,    256, 0, stream>>>(M, e, a, w, part, Mn);
    k_reduce   <<<BS,          256, 0, stream>>>(part, r);
}

// Round 9
// 138.254 us; speedup vs baseline: 1.1688x; 1.1688x over previous
//
#include <hip/hip_runtime.h>

#define BS 64
#define NN 2048
#define DD 512
#define ROWS 64
#define BPB (NN / ROWS)   // blocks per batch in k_rw = 32

typedef float f32x4 __attribute__((ext_vector_type(4)));

__device__ __forceinline__ float block_max(float x) {
    __shared__ float sm[4];
    int lane = threadIdx.x & 63, wid = threadIdx.x >> 6;
#pragma unroll
    for (int off = 32; off > 0; off >>= 1) x = fmaxf(x, __shfl_xor(x, off));
    if (lane == 0) sm[wid] = x;
    __syncthreads();
    x = fmaxf(fmaxf(sm[0], sm[1]), fmaxf(sm[2], sm[3]));
    __syncthreads();
    return x;
}
__device__ __forceinline__ float block_sum(float x) {
    __shared__ float sm[4];
    int lane = threadIdx.x & 63, wid = threadIdx.x >> 6;
#pragma unroll
    for (int off = 32; off > 0; off >>= 1) x += __shfl_xor(x, off);
    if (lane == 0) sm[wid] = x;
    __syncthreads();
    x = sm[0] + sm[1] + sm[2] + sm[3];
    __syncthreads();
    return x;
}

// ---------- Kernel 1: content scores (4 rows/wave/iter, 8 loads in flight) ----------
__global__ __launch_bounds__(256) void k_score(const float* __restrict__ M,
                                               const float* __restrict__ kvec,
                                               const float* __restrict__ beta,
                                               float* __restrict__ score) {
    int wave = threadIdx.x >> 6;
    int lane = threadIdx.x & 63;
    int row0 = blockIdx.x * 16 + wave * 4;       // 16 rows/block, 4/wave
    int b    = row0 >> 11;

    const f32x4* kr = (const f32x4*)(kvec + (size_t)b * DD);
    f32x4 k0 = kr[lane], k1 = kr[lane + 64];
    float ssk = k0.x*k0.x + k0.y*k0.y + k0.z*k0.z + k0.w*k0.w
              + k1.x*k1.x + k1.y*k1.y + k1.z*k1.z + k1.w*k1.w;
#pragma unroll
    for (int off = 32; off > 0; off >>= 1) ssk += __shfl_xor(ssk, off);
    float bscale = beta[b];

    f32x4 xa[4], xb[4];
#pragma unroll
    for (int rr = 0; rr < 4; ++rr) {
        const f32x4* Mr = (const f32x4*)(M + ((size_t)row0 + rr) * DD);
        xa[rr] = Mr[lane];
        xb[rr] = Mr[lane + 64];
    }
    float dot[4], ss[4];
#pragma unroll
    for (int rr = 0; rr < 4; ++rr) {
        dot[rr] = xa[rr].x*k0.x + xa[rr].y*k0.y + xa[rr].z*k0.z + xa[rr].w*k0.w
                + xb[rr].x*k1.x + xb[rr].y*k1.y + xb[rr].z*k1.z + xb[rr].w*k1.w;
        ss[rr]  = xa[rr].x*xa[rr].x + xa[rr].y*xa[rr].y + xa[rr].z*xa[rr].z + xa[rr].w*xa[rr].w
                + xb[rr].x*xb[rr].x + xb[rr].y*xb[rr].y + xb[rr].z*xb[rr].z + xb[rr].w*xb[rr].w;
    }
#pragma unroll
    for (int off = 32; off > 0; off >>= 1) {
#pragma unroll
        for (int rr = 0; rr < 4; ++rr) {
            dot[rr] += __shfl_xor(dot[rr], off);
            ss[rr]  += __shfl_xor(ss[rr], off);
        }
    }
    if (lane == 0) {
        f32x4 sc;
        sc.x = bscale * dot[0] * rsqrtf(ss[0] * ssk);
        sc.y = bscale * dot[1] * rsqrtf(ss[1] * ssk);
        sc.z = bscale * dot[2] * rsqrtf(ss[2] * ssk);
        sc.w = bscale * dot[3] * rsqrtf(ss[3] * ssk);
        *(f32x4*)&score[row0] = sc;
    }
}

// ---------- Kernel 2: fused weights (redundant per block) + M_next + partial r ----------
__global__ __launch_bounds__(256) void k_rw(const float* __restrict__ M,
                                            const float* __restrict__ score,
                                            const float* __restrict__ gp,
                                            const float* __restrict__ sp,
                                            const float* __restrict__ yp,
                                            const float* __restrict__ ep,
                                            const float* __restrict__ ap,
                                            const float* __restrict__ w_prev,
                                            float* __restrict__ w_out,
                                            float* __restrict__ part,
                                            float* __restrict__ Mn) {
    __shared__ float v[NN];
    __shared__ float wloc[ROWS];
    __shared__ f32x4 sacc[128];

    int blk = (int)gridDim.x - 1 - (int)blockIdx.x;   // reverse for L3 LRU
    int b   = blk / BPB;
    int q   = blk % BPB;
    int n0  = q * ROWS;
    int t   = threadIdx.x;

    // ===== phase b: softmax + gate + conv + sharpen (redundant per block) =====
    float g = gp[b], y = yp[b];
    float s0 = sp[b * 3 + 0], s1 = sp[b * 3 + 1], s2 = sp[b * 3 + 2];

    float loc[8];
    float mx = -1e30f;
#pragma unroll
    for (int i = 0; i < 8; ++i) {
        loc[i] = score[(size_t)b * NN + t * 8 + i];
        mx = fmaxf(mx, loc[i]);
    }
    mx = block_max(mx);
    float sum = 0.f;
#pragma unroll
    for (int i = 0; i < 8; ++i) {
        loc[i] = __expf(loc[i] - mx);
        sum += loc[i];
    }
    sum = block_sum(sum);
    float inv = 1.f / sum;
#pragma unroll
    for (int i = 0; i < 8; ++i) {
        int n = t * 8 + i;
        v[n] = g * loc[i] * inv + (1.f - g) * w_prev[(size_t)b * NN + n];
    }
    __syncthreads();
    float u[8];
    float psum = 0.f;
#pragma unroll
    for (int i = 0; i < 8; ++i) {
        int n  = t * 8 + i;
        int nm = (n == 0) ? NN - 1 : n - 1;
        int np = (n == NN - 1) ? 0 : n + 1;
        float uu = s2 * v[nm] + s1 * v[n] + s0 * v[np];
        uu = powf(uu, y);
        u[i] = uu;
        psum += uu;
    }
    psum = block_sum(psum);
    float pin = 1.f / psum;
#pragma unroll
    for (int i = 0; i < 8; ++i) {
        int n  = t * 8 + i;
        float wf = u[i] * pin;
        if (q == 0) w_out[(size_t)b * NN + n] = wf;   // one block/batch emits w
        int d = n - n0;
        if (d >= 0 && d < ROWS) wloc[d] = wf;
    }
    __syncthreads();

    // ===== phase c: M_next + partial r, double-buffered register staging =====
    int c  = t & 127;
    int rh = t >> 7;
    const f32x4* e4 = (const f32x4*)(ep + (size_t)b * DD);
    const f32x4* a4 = (const f32x4*)(ap + (size_t)b * DD);
    f32x4 ev = e4[c], av = a4[c];
    f32x4 acc = (f32x4)(0.f);

    const f32x4* Mb  = (const f32x4*)(M  + ((size_t)b * NN + n0) * DD);
    f32x4*       Mnb = (f32x4*)      (Mn + ((size_t)b * NN + n0) * DD);

    float wv0[4];
    f32x4 m40[4];
#pragma unroll
    for (int j = 0; j < 4; ++j) {
        int rr = j * 2 + rh;
        wv0[j] = wloc[rr];
        m40[j] = Mb[(size_t)rr * 128 + c];
    }
#pragma unroll
    for (int i = 0; i < 8; ++i) {
        float wv1[4];
        f32x4 m41[4];
        if (i < 7) {
#pragma unroll
            for (int j = 0; j < 4; ++j) {
                int rr = ((i + 1) * 4 + j) * 2 + rh;
                wv1[j] = wloc[rr];
                m41[j] = Mb[(size_t)rr * 128 + c];
            }
        }
#pragma unroll
        for (int j = 0; j < 4; ++j) {
            int rr = (i * 4 + j) * 2 + rh;
            acc += wv0[j] * m40[j];
            f32x4 o = m40[j] * (1.f - wv0[j] * ev) + wv0[j] * av;
            __builtin_nontemporal_store(o, &Mnb[(size_t)rr * 128 + c]);
        }
#pragma unroll
        for (int j = 0; j < 4; ++j) { wv0[j] = wv1[j]; m40[j] = m41[j]; }
    }

    if (rh == 1) sacc[c] = acc;
    __syncthreads();
    if (rh == 0) {
        acc += sacc[c];
        ((f32x4*)(part + (size_t)blk * DD))[c] = acc;
    }
}

// ---------- Kernel 3: reduce partial r ----------
__global__ __launch_bounds__(256) void k_reduce(const float* __restrict__ part,
                                               float* __restrict__ r) {
    int b  = blockIdx.x;
    int t  = threadIdx.x;
    int c  = t & 127;
    int rh = t >> 7;
    const f32x4* pb = (const f32x4*)(part + (size_t)b * BPB * DD);
    f32x4 acc = (f32x4)(0.f);
    for (int j = rh * (BPB / 2); j < (rh + 1) * (BPB / 2); ++j) {
        acc += pb[(size_t)j * 128 + c];
    }
    __shared__ f32x4 sacc[128];
    if (rh == 1) sacc[c] = acc;
    __syncthreads();
    if (rh == 0) {
        acc += sacc[c];
        ((f32x4*)(r + (size_t)b * DD))[c] = acc;
    }
}

extern "C" void kernel_launch(void* const* d_in, const int* in_sizes, int n_in,
                              void* d_out, int out_size, void* d_ws, size_t ws_size,
                              hipStream_t stream) {
    const float* M      = (const float*)d_in[0];
    const float* k      = (const float*)d_in[1];
    const float* beta   = (const float*)d_in[2];
    const float* g      = (const float*)d_in[3];
    const float* s      = (const float*)d_in[4];
    const float* y      = (const float*)d_in[5];
    const float* e      = (const float*)d_in[6];
    const float* a      = (const float*)d_in[7];
    const float* w_prev = (const float*)d_in[8];

    float* out = (float*)d_out;
    float* r   = out;                       // [BS, DD]
    float* w   = out + BS * DD;             // [BS, NN]
    float* Mn  = out + BS * DD + BS * NN;   // [BS, NN, DD]

    float* score = (float*)d_ws;                 // BS*NN floats   (512 KB)
    float* part  = score + BS * NN;              // BS*BPB*DD floats (4 MB)

    k_score <<<BS * NN / 16, 256, 0, stream>>>(M, k, beta, score);
    k_rw    <<<BS * BPB,     256, 0, stream>>>(M, score, g, s, y, e, a,
                                               w_prev, w, part, Mn);
    k_reduce<<<BS,           256, 0, stream>>>(part, r);
}